// Round 1
// baseline (294.742 us; speedup 1.0000x reference)
//
#include <hip/hip_runtime.h>
#include <math.h>

// ---------------- problem constants ----------------
#define BB 8
#define NN 64
#define F_IN 32
#define F_E 16
#define HH 64        // hidden_state_size H
#define MM 64        // message size M
#define EHD 50       // edge hidden dim
#define TT 12        // l_target
#define RD 200       // readout hidden
#define NL 3

#define KP 52                 // padded edge-MLP hidden rows: 50 real + 1 bias + 1 zero
#define WROWS (KP * MM)       // 3328 rows of Waug[(k,m)][h]
#define RLEN (NN * KP)        // 3328 reduce length for message GEMM
#define NODES (BB * NN)       // 512

// ---------------- workspace layout (floats) ----------------
// Waug:  [WROWS][H]            212992
// h0:    [NODES][H]             32768
// h:     [NODES][H]             32768
// valid: [NODES]                  512
// ug:    [B][N_j][N_i][KP]    1703936
// C:     [NODES][WROWS]       1703936
// total: 3686912 floats = ~14.75 MB
#define OFF_WAUG  0
#define SZ_WAUG   (WROWS * HH)
#define OFF_H0    (OFF_WAUG + SZ_WAUG)
#define OFF_H     (OFF_H0 + NODES * HH)
#define OFF_VALID (OFF_H + NODES * HH)
#define OFF_UG    (OFF_VALID + NODES)
#define SZ_UG     (BB * NN * RLEN)
#define OFF_C     (OFF_UG + SZ_UG)
#define SZ_C      (NODES * WROWS)

// ============================================================
// prep: build Waug (We2 reshaped + be2 row + zero row), h0/h (padded), valid, zero out
// ============================================================
__global__ __launch_bounds__(256) void prep_kernel(const float* __restrict__ h_in,
                                                   const float* __restrict__ We2,
                                                   const float* __restrict__ be2,
                                                   float* __restrict__ ws,
                                                   float* __restrict__ out) {
    int idx = blockIdx.x * 256 + threadIdx.x;
    float* Waug  = ws + OFF_WAUG;
    float* h0    = ws + OFF_H0;
    float* h     = ws + OFF_H;
    float* valid = ws + OFF_VALID;
    if (idx < SZ_WAUG) {
        int km = idx >> 6;          // row (k,m)
        int hv = idx & 63;
        int k  = km >> 6;
        int m  = km & 63;
        float v = 0.0f;
        if (k < EHD)       v = We2[k * (MM * HH) + m * HH + hv];
        else if (k == EHD) v = be2[m * HH + hv];
        Waug[idx] = v;
    } else if (idx < SZ_WAUG + NODES * HH) {
        int t = idx - SZ_WAUG;
        int n = t >> 6;
        int hv = t & 63;
        float v = (hv < F_IN) ? h_in[n * F_IN + hv] : 0.0f;
        h0[t] = v;
        h[t]  = v;
    } else if (idx < SZ_WAUG + NODES * HH + NODES) {
        int n = idx - SZ_WAUG - NODES * HH;
        float s = 0.0f;
        for (int c = 0; c < F_IN; ++c) s += h_in[n * F_IN + c];
        valid[n] = (s > 0.0f) ? 1.0f : 0.0f;
    } else if (idx < SZ_WAUG + NODES * HH + NODES + BB * TT) {
        out[idx - (SZ_WAUG + NODES * HH + NODES)] = 0.0f;
    }
}

// ============================================================
// edge MLP: ug[b][j][i][k] = g[b,i,j] * relu(e[b,i,j]@We1+be1)[k]; k=50 -> g; k=51 -> 0
// one thread per edge, thread order (b, j, i) so ug writes are contiguous
// ============================================================
__global__ __launch_bounds__(256) void edge_kernel(const float* __restrict__ g,
                                                   const float* __restrict__ e,
                                                   const float* __restrict__ We1,
                                                   const float* __restrict__ be1,
                                                   float* __restrict__ ws) {
    __shared__ float w1[F_E * EHD];   // [c][k]
    __shared__ float b1[EHD];
    for (int t = threadIdx.x; t < F_E * EHD; t += 256) w1[t] = We1[t];
    if (threadIdx.x < EHD) b1[threadIdx.x] = be1[threadIdx.x];
    __syncthreads();

    int idx = blockIdx.x * 256 + threadIdx.x;   // (b, j, i)
    int i = idx & 63;
    int j = (idx >> 6) & 63;
    int b = idx >> 12;

    const float* ep = e + ((size_t)((b * NN + i) * NN + j)) * F_E;
    float ev[F_E];
#pragma unroll
    for (int c = 0; c < F_E; c += 4) {
        float4 v = *(const float4*)(ep + c);
        ev[c] = v.x; ev[c + 1] = v.y; ev[c + 2] = v.z; ev[c + 3] = v.w;
    }
    float gv = g[(b * NN + i) * NN + j];

    float acc[EHD];
#pragma unroll
    for (int k = 0; k < EHD; ++k) acc[k] = b1[k];
#pragma unroll
    for (int c = 0; c < F_E; ++c) {
        float evc = ev[c];
#pragma unroll
        for (int k = 0; k < EHD; ++k) acc[k] += evc * w1[c * EHD + k];
    }
    float* ugp = ws + OFF_UG + ((size_t)(b * NN + j) * NN + i) * KP;
#pragma unroll
    for (int k = 0; k < EHD; ++k) ugp[k] = gv * fmaxf(acc[k], 0.0f);
    ugp[EHD]     = gv;   // bias row of Waug (be2 term) weighted by g only
    ugp[EHD + 1] = 0.0f; // zero pad row
}

// ============================================================
// C GEMM: C[node][(k,m)] = sum_h h[node][h] * Waug[(k,m)][h]
// block tile: 32 nodes x 128 rows, K=64. 256 threads, 4x4 per thread.
// Waug tile XOR-swizzled in LDS to avoid the stride-64 bank conflict.
// ============================================================
#define CG_BM 32
#define CG_BN 128
__global__ __launch_bounds__(256) void cgemm_kernel(float* __restrict__ ws) {
    const float* h    = ws + OFF_H;
    const float* Waug = ws + OFF_WAUG;
    float* C          = ws + OFF_C;

    __shared__ float hs[CG_BM * HH];     // linear, read broadcast
    __shared__ float wsh[CG_BN * HH];    // float4-slot swizzled

    int tid = threadIdx.x;
    int kt = blockIdx.x;   // 0..25 row tiles
    int nt = blockIdx.y;   // 0..15 node tiles

    {   // stage h tile (contiguous 2048 floats)
        const float4* src = (const float4*)(h + nt * CG_BM * HH);
        float4* dst = (float4*)hs;
#pragma unroll
        for (int q = 0; q < 2; ++q) dst[tid + q * 256] = src[tid + q * 256];
    }
    {   // stage Waug tile (contiguous 8192 floats) with slot swizzle
        const float4* src = (const float4*)(Waug + (size_t)kt * CG_BN * HH);
        float4* dst = (float4*)wsh;
#pragma unroll
        for (int q = 0; q < 8; ++q) {
            int fi = tid + q * 256;      // float4 index: row = fi>>4, slot = fi&15
            int row = fi >> 4, slot = fi & 15;
            dst[(row << 4) | (slot ^ (row & 15))] = src[fi];
        }
    }
    __syncthreads();

    int cg = tid & 31;   // row-lane group (rows cg + 32p)
    int rg = tid >> 5;   // node group (nodes rg*4+q)
    float acc[4][4];
#pragma unroll
    for (int q = 0; q < 4; ++q)
#pragma unroll
        for (int p = 0; p < 4; ++p) acc[q][p] = 0.0f;

#pragma unroll
    for (int hv = 0; hv < HH; hv += 4) {
        int slot = hv >> 2;
        float4 a[4], w[4];
#pragma unroll
        for (int q = 0; q < 4; ++q)
            a[q] = *(const float4*)(hs + (rg * 4 + q) * HH + hv);
#pragma unroll
        for (int p = 0; p < 4; ++p) {
            int row = cg + 32 * p;
            w[p] = ((const float4*)wsh)[(row << 4) | (slot ^ (row & 15))];
        }
#pragma unroll
        for (int q = 0; q < 4; ++q)
#pragma unroll
            for (int p = 0; p < 4; ++p)
                acc[q][p] += a[q].x * w[p].x + a[q].y * w[p].y +
                             a[q].z * w[p].z + a[q].w * w[p].w;
    }

#pragma unroll
    for (int q = 0; q < 4; ++q) {
        int node = nt * CG_BM + rg * 4 + q;
#pragma unroll
        for (int p = 0; p < 4; ++p) {
            int km = kt * CG_BN + cg + 32 * p;
            C[(size_t)node * WROWS + km] = acc[q][p];
        }
    }
}

// ============================================================
// message + GRU fused: one block per (b,j).
// phase A: m[m] = sum_{i,k} ug[b,j,i,k] * C[(b,i)][(k,m)]  (4 waves split i-range)
// phase B: GRU cell for node (b,j), in-place h update (own row only).
// ============================================================
__global__ __launch_bounds__(256) void msg_gru_kernel(const float* __restrict__ W_ih,
                                                      const float* __restrict__ W_hh,
                                                      const float* __restrict__ b_ih,
                                                      const float* __restrict__ b_hh,
                                                      float* __restrict__ ws) {
    int bj = blockIdx.x;          // 0..511
    int b = bj >> 6;

    const float* C  = ws + OFF_C + (size_t)b * NN * WROWS;
    const float* ug = ws + OFF_UG + (size_t)bj * RLEN;
    float* h            = ws + OFF_H;
    const float* valid  = ws + OFF_VALID;

    __shared__ float mpart[4][MM];
    __shared__ float mv[MM];
    __shared__ float hv[HH];
    __shared__ float gi_s[3 * HH], gh_s[3 * HH];

    int lane = threadIdx.x & 63;
    int grp  = threadIdx.x >> 6;

    if (threadIdx.x < HH) hv[threadIdx.x] = h[(size_t)bj * HH + threadIdx.x];

    float a0 = 0.f, a1 = 0.f, a2 = 0.f, a3 = 0.f;
    for (int i = grp * 16; i < grp * 16 + 16; ++i) {
        const float* Crow  = C + (size_t)i * WROWS + lane;
        const float* ugrow = ug + i * KP;
#pragma unroll
        for (int k = 0; k < KP; k += 4) {
            a0 += ugrow[k + 0] * Crow[(k + 0) * MM];
            a1 += ugrow[k + 1] * Crow[(k + 1) * MM];
            a2 += ugrow[k + 2] * Crow[(k + 2) * MM];
            a3 += ugrow[k + 3] * Crow[(k + 3) * MM];
        }
    }
    mpart[grp][lane] = (a0 + a1) + (a2 + a3);
    __syncthreads();

    if (threadIdx.x < MM)
        mv[threadIdx.x] = mpart[0][threadIdx.x] + mpart[1][threadIdx.x] +
                          mpart[2][threadIdx.x] + mpart[3][threadIdx.x];
    __syncthreads();

    if (threadIdx.x < 3 * HH) {
        int x = threadIdx.x;
        float gi = b_ih[x], gh = b_hh[x];
        const float4* wi = (const float4*)(W_ih + x * MM);
        const float4* wh = (const float4*)(W_hh + x * HH);
#pragma unroll
        for (int c = 0; c < HH / 4; ++c) {
            float4 aw = wi[c], bw = wh[c];
            gi += aw.x * mv[c * 4] + aw.y * mv[c * 4 + 1] + aw.z * mv[c * 4 + 2] + aw.w * mv[c * 4 + 3];
            gh += bw.x * hv[c * 4] + bw.y * hv[c * 4 + 1] + bw.z * hv[c * 4 + 2] + bw.w * hv[c * 4 + 3];
        }
        gi_s[x] = gi;
        gh_s[x] = gh;
    }
    __syncthreads();

    if (threadIdx.x < HH) {
        int t = threadIdx.x;
        float r = 1.0f / (1.0f + expf(-(gi_s[t] + gh_s[t])));
        float z = 1.0f / (1.0f + expf(-(gi_s[HH + t] + gh_s[HH + t])));
        float n = tanhf(gi_s[2 * HH + t] + r * gh_s[2 * HH + t]);
        float hn = (1.0f - z) * n + z * hv[t];
        h[(size_t)bj * HH + t] = hn * valid[bj];
    }
}

// ============================================================
// readout: per node, i-net sigmoid(relu(cat@Wi1+bi1)@Wi2+bi2), j-net relu(h@Wj1+bj1)@Wj2+bj2
// contrib = valid * i * j, atomicAdd into out[b][t]. one wave per node.
// ============================================================
__global__ __launch_bounds__(64) void readout_kernel(const float* __restrict__ Wi1,
                                                     const float* __restrict__ bi1,
                                                     const float* __restrict__ Wi2,
                                                     const float* __restrict__ bi2,
                                                     const float* __restrict__ Wj1,
                                                     const float* __restrict__ bj1,
                                                     const float* __restrict__ Wj2,
                                                     const float* __restrict__ bj2,
                                                     float* __restrict__ ws,
                                                     float* __restrict__ out) {
    int node = blockIdx.x;   // 0..511
    int b = node >> 6;
    int t = threadIdx.x;     // 0..63

    __shared__ float cat[2 * HH];
    __shared__ float ih[RD], jh[RD];

    const float* h  = ws + OFF_H;
    const float* h0 = ws + OFF_H0;
    const float* valid = ws + OFF_VALID;

    cat[t]      = h[(size_t)node * HH + t];
    cat[64 + t] = h0[(size_t)node * HH + t];
    __syncthreads();

    // ---- i hidden: units t, t+64, t+128, (t+192 if t<8) ----
    bool has3 = (t + 192 < RD);
    int u3 = has3 ? (t + 192) : 0;
    float a0 = bi1[t], a1 = bi1[t + 64], a2 = bi1[t + 128], a3 = has3 ? bi1[u3] : 0.f;
    for (int c = 0; c < 2 * HH; ++c) {
        float cv = cat[c];
        const float* wr = Wi1 + c * RD;
        a0 += cv * wr[t];
        a1 += cv * wr[t + 64];
        a2 += cv * wr[t + 128];
        a3 += cv * wr[u3];
    }
    ih[t] = fmaxf(a0, 0.f); ih[t + 64] = fmaxf(a1, 0.f); ih[t + 128] = fmaxf(a2, 0.f);
    if (has3) ih[u3] = fmaxf(a3, 0.f);

    // ---- j hidden ----
    float c0 = bj1[t], c1 = bj1[t + 64], c2 = bj1[t + 128], c3 = has3 ? bj1[u3] : 0.f;
    for (int c = 0; c < HH; ++c) {
        float hvv = cat[c];  // h part of cat
        const float* wr = Wj1 + c * RD;
        c0 += hvv * wr[t];
        c1 += hvv * wr[t + 64];
        c2 += hvv * wr[t + 128];
        c3 += hvv * wr[u3];
    }
    jh[t] = fmaxf(c0, 0.f); jh[t + 64] = fmaxf(c1, 0.f); jh[t + 128] = fmaxf(c2, 0.f);
    if (has3) jh[u3] = fmaxf(c3, 0.f);
    __syncthreads();

    if (t < TT) {
        float i2 = bi2[t], j2 = bj2[t];
        for (int u = 0; u < RD; ++u) {
            i2 += ih[u] * Wi2[u * TT + t];
            j2 += jh[u] * Wj2[u * TT + t];
        }
        float sig = 1.0f / (1.0f + expf(-i2));
        float contrib = valid[node] * sig * j2;
        atomicAdd(&out[b * TT + t], contrib);
    }
}

// ============================================================
extern "C" void kernel_launch(void* const* d_in, const int* in_sizes, int n_in,
                              void* d_out, int out_size, void* d_ws, size_t ws_size,
                              hipStream_t stream) {
    (void)in_sizes; (void)n_in; (void)out_size; (void)ws_size;
    const float* g    = (const float*)d_in[0];
    const float* h_in = (const float*)d_in[1];
    const float* e    = (const float*)d_in[2];
    const float* We1  = (const float*)d_in[3];
    const float* be1  = (const float*)d_in[4];
    const float* We2  = (const float*)d_in[5];
    const float* be2  = (const float*)d_in[6];
    const float* W_ih = (const float*)d_in[7];
    const float* W_hh = (const float*)d_in[8];
    const float* b_ih = (const float*)d_in[9];
    const float* b_hh = (const float*)d_in[10];
    const float* Wi1  = (const float*)d_in[11];
    const float* bi1  = (const float*)d_in[12];
    const float* Wi2  = (const float*)d_in[13];
    const float* bi2  = (const float*)d_in[14];
    const float* Wj1  = (const float*)d_in[15];
    const float* bj1  = (const float*)d_in[16];
    const float* Wj2  = (const float*)d_in[17];
    const float* bj2  = (const float*)d_in[18];
    float* out = (float*)d_out;
    float* ws  = (float*)d_ws;

    // prep covers Waug + h0/h + valid + out-zero ranges
    const int prep_elems = SZ_WAUG + NODES * HH + NODES + BB * TT;
    prep_kernel<<<(prep_elems + 255) / 256, 256, 0, stream>>>(h_in, We2, be2, ws, out);
    edge_kernel<<<(BB * NN * NN) / 256, 256, 0, stream>>>(g, e, We1, be1, ws);

    for (int l = 0; l < NL; ++l) {
        cgemm_kernel<<<dim3(WROWS / CG_BN, NODES / CG_BM), 256, 0, stream>>>(ws);
        msg_gru_kernel<<<NODES, 256, 0, stream>>>(W_ih, W_hh, b_ih, b_hh, ws);
    }

    readout_kernel<<<NODES, 64, 0, stream>>>(Wi1, bi1, Wi2, bi2, Wj1, bj1, Wj2, bj2, ws, out);
}

// Round 2
// 214.709 us; speedup vs baseline: 1.3728x; 1.3728x over previous
//
#include <hip/hip_runtime.h>
#include <math.h>

// ---------------- problem constants ----------------
#define BB 8
#define NN 64
#define F_IN 32
#define F_E 16
#define HH 64        // hidden_state_size H
#define MM 64        // message size M
#define EHD 50       // edge hidden dim
#define TT 12        // l_target
#define RD 200       // readout hidden
#define NL 3

#define KP 52                 // padded edge-MLP hidden rows: 50 real + 1 bias + 1 zero
#define WROWS (KP * MM)       // 3328 rows of Waug[(k,m)][h]
#define RLEN (NN * KP)        // 3328 reduce length for message GEMM
#define NODES (BB * NN)       // 512
#define IG 32                 // i-groups per batch (2 i's each) for split-K message GEMM

// ---------------- workspace layout (floats) ----------------
// Waug:   [WROWS][H]            212992
// h0:     [NODES][H]             32768
// h:      [NODES][H]             32768
// valid:  [NODES]                  512
// ug:     [B][N_j][N_i][KP]    1703936
// C:      [NODES][WROWS]       1703936
// m_part: [B][IG][N_j][M]      1048576
// total: 4735488 floats = ~18.9 MB
#define OFF_WAUG  0
#define SZ_WAUG   (WROWS * HH)
#define OFF_H0    (OFF_WAUG + SZ_WAUG)
#define OFF_H     (OFF_H0 + NODES * HH)
#define OFF_VALID (OFF_H + NODES * HH)
#define OFF_UG    (OFF_VALID + NODES)
#define SZ_UG     (BB * NN * RLEN)
#define OFF_C     (OFF_UG + SZ_UG)
#define SZ_C      (NODES * WROWS)
#define OFF_MPART (OFF_C + SZ_C)
#define SZ_MPART  (BB * IG * NN * MM)

// ============================================================
// prep: build Waug (We2 reshaped + be2 row + zero row), h0/h (padded), valid, zero out
// ============================================================
__global__ __launch_bounds__(256) void prep_kernel(const float* __restrict__ h_in,
                                                   const float* __restrict__ We2,
                                                   const float* __restrict__ be2,
                                                   float* __restrict__ ws,
                                                   float* __restrict__ out) {
    int idx = blockIdx.x * 256 + threadIdx.x;
    float* Waug  = ws + OFF_WAUG;
    float* h0    = ws + OFF_H0;
    float* h     = ws + OFF_H;
    float* valid = ws + OFF_VALID;
    if (idx < SZ_WAUG) {
        int km = idx >> 6;          // row (k,m)
        int hv = idx & 63;
        int k  = km >> 6;
        int m  = km & 63;
        float v = 0.0f;
        if (k < EHD)       v = We2[k * (MM * HH) + m * HH + hv];
        else if (k == EHD) v = be2[m * HH + hv];
        Waug[idx] = v;
    } else if (idx < SZ_WAUG + NODES * HH) {
        int t = idx - SZ_WAUG;
        int n = t >> 6;
        int hv = t & 63;
        float v = (hv < F_IN) ? h_in[n * F_IN + hv] : 0.0f;
        h0[t] = v;
        h[t]  = v;
    } else if (idx < SZ_WAUG + NODES * HH + NODES) {
        int n = idx - SZ_WAUG - NODES * HH;
        float s = 0.0f;
        for (int c = 0; c < F_IN; ++c) s += h_in[n * F_IN + c];
        valid[n] = (s > 0.0f) ? 1.0f : 0.0f;
    } else if (idx < SZ_WAUG + NODES * HH + NODES + BB * TT) {
        out[idx - (SZ_WAUG + NODES * HH + NODES)] = 0.0f;
    }
}

// ============================================================
// edge MLP: ug[b][j][i][k] = g[b,i,j] * relu(e[b,i,j]@We1+be1)[k]; k=50 -> g; k=51 -> 0
// ============================================================
__global__ __launch_bounds__(256) void edge_kernel(const float* __restrict__ g,
                                                   const float* __restrict__ e,
                                                   const float* __restrict__ We1,
                                                   const float* __restrict__ be1,
                                                   float* __restrict__ ws) {
    __shared__ float w1[F_E * EHD];   // [c][k]
    __shared__ float b1[EHD];
    for (int t = threadIdx.x; t < F_E * EHD; t += 256) w1[t] = We1[t];
    if (threadIdx.x < EHD) b1[threadIdx.x] = be1[threadIdx.x];
    __syncthreads();

    int idx = blockIdx.x * 256 + threadIdx.x;   // (b, j, i)
    int i = idx & 63;
    int j = (idx >> 6) & 63;
    int b = idx >> 12;

    const float* ep = e + ((size_t)((b * NN + i) * NN + j)) * F_E;
    float ev[F_E];
#pragma unroll
    for (int c = 0; c < F_E; c += 4) {
        float4 v = *(const float4*)(ep + c);
        ev[c] = v.x; ev[c + 1] = v.y; ev[c + 2] = v.z; ev[c + 3] = v.w;
    }
    float gv = g[(b * NN + i) * NN + j];

    float acc[EHD];
#pragma unroll
    for (int k = 0; k < EHD; ++k) acc[k] = b1[k];
#pragma unroll
    for (int c = 0; c < F_E; ++c) {
        float evc = ev[c];
#pragma unroll
        for (int k = 0; k < EHD; ++k) acc[k] += evc * w1[c * EHD + k];
    }
    float* ugp = ws + OFF_UG + ((size_t)(b * NN + j) * NN + i) * KP;
#pragma unroll
    for (int k = 0; k < EHD; ++k) ugp[k] = gv * fmaxf(acc[k], 0.0f);
    ugp[EHD]     = gv;   // bias row of Waug (be2 term) weighted by g only
    ugp[EHD + 1] = 0.0f; // zero pad row
}

// ============================================================
// C GEMM: C[node][(k,m)] = sum_h h[node][h] * Waug[(k,m)][h]
// block tile: 32 nodes x 128 rows, K=64. 256 threads, 4x4 per thread.
// ============================================================
#define CG_BM 32
#define CG_BN 128
__global__ __launch_bounds__(256) void cgemm_kernel(float* __restrict__ ws) {
    const float* h    = ws + OFF_H;
    const float* Waug = ws + OFF_WAUG;
    float* C          = ws + OFF_C;

    __shared__ float hs[CG_BM * HH];     // linear, read broadcast
    __shared__ float wsh[CG_BN * HH];    // float4-slot swizzled

    int tid = threadIdx.x;
    int kt = blockIdx.x;   // 0..25 row tiles
    int nt = blockIdx.y;   // 0..15 node tiles

    {   // stage h tile (contiguous 2048 floats)
        const float4* src = (const float4*)(h + nt * CG_BM * HH);
        float4* dst = (float4*)hs;
#pragma unroll
        for (int q = 0; q < 2; ++q) dst[tid + q * 256] = src[tid + q * 256];
    }
    {   // stage Waug tile (contiguous 8192 floats) with slot swizzle
        const float4* src = (const float4*)(Waug + (size_t)kt * CG_BN * HH);
        float4* dst = (float4*)wsh;
#pragma unroll
        for (int q = 0; q < 8; ++q) {
            int fi = tid + q * 256;      // float4 index: row = fi>>4, slot = fi&15
            int row = fi >> 4, slot = fi & 15;
            dst[(row << 4) | (slot ^ (row & 15))] = src[fi];
        }
    }
    __syncthreads();

    int cg = tid & 31;   // row-lane group (rows cg + 32p)
    int rg = tid >> 5;   // node group (nodes rg*4+q)
    float acc[4][4];
#pragma unroll
    for (int q = 0; q < 4; ++q)
#pragma unroll
        for (int p = 0; p < 4; ++p) acc[q][p] = 0.0f;

#pragma unroll
    for (int hv = 0; hv < HH; hv += 4) {
        int slot = hv >> 2;
        float4 a[4], w[4];
#pragma unroll
        for (int q = 0; q < 4; ++q)
            a[q] = *(const float4*)(hs + (rg * 4 + q) * HH + hv);
#pragma unroll
        for (int p = 0; p < 4; ++p) {
            int row = cg + 32 * p;
            w[p] = ((const float4*)wsh)[(row << 4) | (slot ^ (row & 15))];
        }
#pragma unroll
        for (int q = 0; q < 4; ++q)
#pragma unroll
            for (int p = 0; p < 4; ++p)
                acc[q][p] += a[q].x * w[p].x + a[q].y * w[p].y +
                             a[q].z * w[p].z + a[q].w * w[p].w;
    }

#pragma unroll
    for (int q = 0; q < 4; ++q) {
        int node = nt * CG_BM + rg * 4 + q;
#pragma unroll
        for (int p = 0; p < 4; ++p) {
            int km = kt * CG_BN + cg + 32 * p;
            C[(size_t)node * WROWS + km] = acc[q][p];
        }
    }
}

// ============================================================
// msg_tiled: split-K message GEMM.
// block = (b, ig); handles i in {2*ig, 2*ig+1}, K = 104.
// Computes full 64j x 64m partial tile:
//   m_part[b][ig][j][m] = sum_{kk<104} ug[b,j,(i0*52+kk)] * C[(b,i0)..][kk*64+m]
// LDS: ug transposed [104][64j] (broadcast reads) + C linear [104][64m].
// 256 threads, 4x4 microtile: 2 ds_read_b128 + 16 FMA per k.
// ============================================================
__global__ __launch_bounds__(256) void msg_tiled_kernel(float* __restrict__ ws) {
    int blk = blockIdx.x;          // 0..255
    int b   = blk >> 5;
    int ig  = blk & 31;
    int i0  = ig * 2;

    const float* Cg  = ws + OFF_C  + (size_t)(b * NN + i0) * WROWS;      // 6656 contiguous
    const float* ugg = ws + OFF_UG + (size_t)(b * NN) * RLEN + i0 * KP;  // per-j stride RLEN
    float* mp = ws + OFF_MPART + (size_t)(b * IG + ig) * (NN * MM);

    __shared__ float ug_t[104][64];   // [kk][j]
    __shared__ float C_s[104 * 64];   // [kk][m]

    int tid = threadIdx.x;
    {   // stage C linearly (1664 float4)
        const float4* src = (const float4*)Cg;
        float4* dst = (float4*)C_s;
        for (int f = tid; f < 1664; f += 256) dst[f] = src[f];
    }
    {   // stage ug transposed: f -> (j, kq)
        for (int f = tid; f < 1664; f += 256) {
            int j = f / 26, kq = f - j * 26;
            float4 v = *(const float4*)(ugg + (size_t)j * RLEN + kq * 4);
            ug_t[kq * 4 + 0][j] = v.x;
            ug_t[kq * 4 + 1][j] = v.y;
            ug_t[kq * 4 + 2][j] = v.z;
            ug_t[kq * 4 + 3][j] = v.w;
        }
    }
    __syncthreads();

    int tx = tid & 15;   // m-group: columns tx*4 .. tx*4+3
    int ty = tid >> 4;   // j-group: rows    ty*4 .. ty*4+3
    float acc[4][4];
#pragma unroll
    for (int q = 0; q < 4; ++q)
#pragma unroll
        for (int p = 0; p < 4; ++p) acc[q][p] = 0.0f;

    const float4* C4 = (const float4*)C_s;
#pragma unroll 4
    for (int k = 0; k < 104; ++k) {
        float4 bv = C4[k * 16 + tx];
        float4 av = *(const float4*)(&ug_t[k][ty * 4]);
        acc[0][0] += av.x * bv.x; acc[0][1] += av.x * bv.y; acc[0][2] += av.x * bv.z; acc[0][3] += av.x * bv.w;
        acc[1][0] += av.y * bv.x; acc[1][1] += av.y * bv.y; acc[1][2] += av.y * bv.z; acc[1][3] += av.y * bv.w;
        acc[2][0] += av.z * bv.x; acc[2][1] += av.z * bv.y; acc[2][2] += av.z * bv.z; acc[2][3] += av.z * bv.w;
        acc[3][0] += av.w * bv.x; acc[3][1] += av.w * bv.y; acc[3][2] += av.w * bv.z; acc[3][3] += av.w * bv.w;
    }

#pragma unroll
    for (int q = 0; q < 4; ++q) {
        float4 o; o.x = acc[q][0]; o.y = acc[q][1]; o.z = acc[q][2]; o.w = acc[q][3];
        *(float4*)(mp + (size_t)(ty * 4 + q) * MM + tx * 4) = o;
    }
}

// ============================================================
// gru_reduce: sum the IG partials per (b,j) then run the GRU cell.
// block per (b,j), 256 threads (4 waves; wave w reduces 8 partials).
// ============================================================
__global__ __launch_bounds__(256) void gru_reduce_kernel(const float* __restrict__ W_ih,
                                                         const float* __restrict__ W_hh,
                                                         const float* __restrict__ b_ih,
                                                         const float* __restrict__ b_hh,
                                                         float* __restrict__ ws) {
    int bj = blockIdx.x;          // 0..511
    int b = bj >> 6;
    int j = bj & 63;

    const float* mpart_g = ws + OFF_MPART;
    float* h           = ws + OFF_H;
    const float* valid = ws + OFF_VALID;

    __shared__ float mpart[4][MM];
    __shared__ float mv[MM];
    __shared__ float hv[HH];
    __shared__ float gi_s[3 * HH], gh_s[3 * HH];

    int lane = threadIdx.x & 63;
    int w    = threadIdx.x >> 6;

    if (threadIdx.x < HH) hv[threadIdx.x] = h[(size_t)bj * HH + threadIdx.x];

    float s = 0.0f;
#pragma unroll
    for (int q = 0; q < 8; ++q) {
        int ig = w * 8 + q;
        s += mpart_g[((size_t)(b * IG + ig) * NN + j) * MM + lane];
    }
    mpart[w][lane] = s;
    __syncthreads();

    if (threadIdx.x < MM)
        mv[threadIdx.x] = mpart[0][threadIdx.x] + mpart[1][threadIdx.x] +
                          mpart[2][threadIdx.x] + mpart[3][threadIdx.x];
    __syncthreads();

    if (threadIdx.x < 3 * HH) {
        int x = threadIdx.x;
        float gi = b_ih[x], gh = b_hh[x];
        const float4* wi = (const float4*)(W_ih + x * MM);
        const float4* wh = (const float4*)(W_hh + x * HH);
#pragma unroll
        for (int c = 0; c < HH / 4; ++c) {
            float4 aw = wi[c], bw = wh[c];
            gi += aw.x * mv[c * 4] + aw.y * mv[c * 4 + 1] + aw.z * mv[c * 4 + 2] + aw.w * mv[c * 4 + 3];
            gh += bw.x * hv[c * 4] + bw.y * hv[c * 4 + 1] + bw.z * hv[c * 4 + 2] + bw.w * hv[c * 4 + 3];
        }
        gi_s[x] = gi;
        gh_s[x] = gh;
    }
    __syncthreads();

    if (threadIdx.x < HH) {
        int t = threadIdx.x;
        float r = 1.0f / (1.0f + expf(-(gi_s[t] + gh_s[t])));
        float z = 1.0f / (1.0f + expf(-(gi_s[HH + t] + gh_s[HH + t])));
        float n = tanhf(gi_s[2 * HH + t] + r * gh_s[2 * HH + t]);
        float hn = (1.0f - z) * n + z * hv[t];
        h[(size_t)bj * HH + t] = hn * valid[bj];
    }
}

// ============================================================
// readout
// ============================================================
__global__ __launch_bounds__(64) void readout_kernel(const float* __restrict__ Wi1,
                                                     const float* __restrict__ bi1,
                                                     const float* __restrict__ Wi2,
                                                     const float* __restrict__ bi2,
                                                     const float* __restrict__ Wj1,
                                                     const float* __restrict__ bj1,
                                                     const float* __restrict__ Wj2,
                                                     const float* __restrict__ bj2,
                                                     float* __restrict__ ws,
                                                     float* __restrict__ out) {
    int node = blockIdx.x;   // 0..511
    int b = node >> 6;
    int t = threadIdx.x;     // 0..63

    __shared__ float cat[2 * HH];
    __shared__ float ih[RD], jh[RD];

    const float* h  = ws + OFF_H;
    const float* h0 = ws + OFF_H0;
    const float* valid = ws + OFF_VALID;

    cat[t]      = h[(size_t)node * HH + t];
    cat[64 + t] = h0[(size_t)node * HH + t];
    __syncthreads();

    bool has3 = (t + 192 < RD);
    int u3 = has3 ? (t + 192) : 0;
    float a0 = bi1[t], a1 = bi1[t + 64], a2 = bi1[t + 128], a3 = has3 ? bi1[u3] : 0.f;
    for (int c = 0; c < 2 * HH; ++c) {
        float cv = cat[c];
        const float* wr = Wi1 + c * RD;
        a0 += cv * wr[t];
        a1 += cv * wr[t + 64];
        a2 += cv * wr[t + 128];
        a3 += cv * wr[u3];
    }
    ih[t] = fmaxf(a0, 0.f); ih[t + 64] = fmaxf(a1, 0.f); ih[t + 128] = fmaxf(a2, 0.f);
    if (has3) ih[u3] = fmaxf(a3, 0.f);

    float c0 = bj1[t], c1 = bj1[t + 64], c2 = bj1[t + 128], c3 = has3 ? bj1[u3] : 0.f;
    for (int c = 0; c < HH; ++c) {
        float hvv = cat[c];  // h part of cat
        const float* wr = Wj1 + c * RD;
        c0 += hvv * wr[t];
        c1 += hvv * wr[t + 64];
        c2 += hvv * wr[t + 128];
        c3 += hvv * wr[u3];
    }
    jh[t] = fmaxf(c0, 0.f); jh[t + 64] = fmaxf(c1, 0.f); jh[t + 128] = fmaxf(c2, 0.f);
    if (has3) jh[u3] = fmaxf(c3, 0.f);
    __syncthreads();

    if (t < TT) {
        float i2 = bi2[t], j2 = bj2[t];
        for (int u = 0; u < RD; ++u) {
            i2 += ih[u] * Wi2[u * TT + t];
            j2 += jh[u] * Wj2[u * TT + t];
        }
        float sig = 1.0f / (1.0f + expf(-i2));
        float contrib = valid[node] * sig * j2;
        atomicAdd(&out[b * TT + t], contrib);
    }
}

// ============================================================
extern "C" void kernel_launch(void* const* d_in, const int* in_sizes, int n_in,
                              void* d_out, int out_size, void* d_ws, size_t ws_size,
                              hipStream_t stream) {
    (void)in_sizes; (void)n_in; (void)out_size; (void)ws_size;
    const float* g    = (const float*)d_in[0];
    const float* h_in = (const float*)d_in[1];
    const float* e    = (const float*)d_in[2];
    const float* We1  = (const float*)d_in[3];
    const float* be1  = (const float*)d_in[4];
    const float* We2  = (const float*)d_in[5];
    const float* be2  = (const float*)d_in[6];
    const float* W_ih = (const float*)d_in[7];
    const float* W_hh = (const float*)d_in[8];
    const float* b_ih = (const float*)d_in[9];
    const float* b_hh = (const float*)d_in[10];
    const float* Wi1  = (const float*)d_in[11];
    const float* bi1  = (const float*)d_in[12];
    const float* Wi2  = (const float*)d_in[13];
    const float* bi2  = (const float*)d_in[14];
    const float* Wj1  = (const float*)d_in[15];
    const float* bj1  = (const float*)d_in[16];
    const float* Wj2  = (const float*)d_in[17];
    const float* bj2  = (const float*)d_in[18];
    float* out = (float*)d_out;
    float* ws  = (float*)d_ws;

    const int prep_elems = SZ_WAUG + NODES * HH + NODES + BB * TT;
    prep_kernel<<<(prep_elems + 255) / 256, 256, 0, stream>>>(h_in, We2, be2, ws, out);
    edge_kernel<<<(BB * NN * NN) / 256, 256, 0, stream>>>(g, e, We1, be1, ws);

    for (int l = 0; l < NL; ++l) {
        cgemm_kernel<<<dim3(WROWS / CG_BN, NODES / CG_BM), 256, 0, stream>>>(ws);
        msg_tiled_kernel<<<BB * IG, 256, 0, stream>>>(ws);
        gru_reduce_kernel<<<NODES, 256, 0, stream>>>(W_ih, W_hh, b_ih, b_hh, ws);
    }

    readout_kernel<<<NODES, 64, 0, stream>>>(Wi1, bi1, Wi2, bi2, Wj1, bj1, Wj2, bj2, ws, out);
}